// Round 2
// baseline (1088.597 us; speedup 1.0000x reference)
//
#include <hip/hip_runtime.h>
#include <hip/hip_bf16.h>

#define NN 100000
#define NE 3200000
// D_IN = D_HID = 128, D_OUT = 64

// ---------------- CSR build ----------------

__global__ void k_hist(const int* __restrict__ dst, int* __restrict__ cnt) {
    int stride = gridDim.x * blockDim.x;
    for (int i = blockIdx.x * blockDim.x + threadIdx.x; i < NE; i += stride)
        atomicAdd(&cnt[dst[i]], 1);
}

// inclusive scan per 1024-block, block totals to bsum
__global__ __launch_bounds__(1024) void k_scan_block(const int* __restrict__ cnt,
                                                     int* __restrict__ incl,
                                                     int* __restrict__ bsum, int n) {
    __shared__ int s[1024];
    int t = threadIdx.x, i = blockIdx.x * 1024 + t;
    int v = (i < n) ? cnt[i] : 0;
    s[t] = v; __syncthreads();
    for (int off = 1; off < 1024; off <<= 1) {
        int x = (t >= off) ? s[t - off] : 0;
        __syncthreads();
        s[t] += x;
        __syncthreads();
    }
    if (i < n) incl[i] = s[t];
    if (t == 1023) bsum[blockIdx.x] = s[t];
}

// exclusive scan of block sums (nb <= 128), one block of 128 threads
__global__ void k_scan_bsum(int* __restrict__ bsum, int nb) {
    __shared__ int s[128];
    int t = threadIdx.x;
    int v = (t < nb) ? bsum[t] : 0;
    s[t] = v; __syncthreads();
    for (int off = 1; off < 128; off <<= 1) {
        int x = (t >= off) ? s[t - off] : 0;
        __syncthreads();
        s[t] += x;
        __syncthreads();
    }
    if (t < nb) bsum[t] = s[t] - v;  // exclusive
}

__global__ void k_offs(const int* __restrict__ incl, const int* __restrict__ bsum,
                       int* __restrict__ offs, int n) {
    int i = blockIdx.x * blockDim.x + threadIdx.x;
    if (i < n) offs[i + 1] = incl[i] + bsum[i >> 10];
    if (i == 0) offs[0] = 0;
}

__global__ void k_fill(const int* __restrict__ src, const int* __restrict__ dst,
                       const float* __restrict__ ew, int* __restrict__ cursor,
                       int* __restrict__ csr_s, float* __restrict__ csr_w) {
    int stride = gridDim.x * blockDim.x;
    for (int i = blockIdx.x * blockDim.x + threadIdx.x; i < NE; i += stride) {
        int d = dst[i];
        int p = atomicAdd(&cursor[d], 1);
        csr_s[p] = src[i];
        csr_w[p] = ew[i];
    }
}

// ---------------- fused dual f32 GEMM ----------------
// Y1[N][BN] = X[N][128] @ W1[BN][128]^T ; Y2 likewise from W2.
// 256 threads; per-thread 4 nodes x 8 dims (split 4+4 across halves of BN
// to keep wt reads at 2-way bank aliasing = free).

template <int BM, int BN, int KC>
__global__ __launch_bounds__(256) void k_gemm_dual(const float* __restrict__ X,
                                                   const float* __restrict__ W1,
                                                   const float* __restrict__ W2,
                                                   float* __restrict__ Y1,
                                                   float* __restrict__ Y2, int N) {
    constexpr int TD = BN / 8;        // threads along dim axis
    constexpr int TN = 256 / TD;      // thread groups along node axis
    static_assert(BM / TN == 4, "4 nodes per thread");
    constexpr int KPF = KC / 4;       // float4s per row chunk
    constexpr int XLD = BM * KC / (4 * 256);
    constexpr int WLD = BN * KC / (4 * 256);
    static_assert(XLD * 4 * 256 == BM * KC && WLD * 4 * 256 == BN * KC);

    __shared__ float xsT[KC][BM + 4];
    __shared__ float wt1[KC][BN + 4];
    __shared__ float wt2[KC][BN + 4];

    const int tid = threadIdx.x;
    const int td = tid % TD, tn = tid / TD;
    const int n0 = tn * 4;
    const int d0 = td * 4;            // lower-half dims
    const int d1 = BN / 2 + td * 4;   // upper-half dims
    const int gn0 = blockIdx.x * BM;

    float acc1[4][8], acc2[4][8];
#pragma unroll
    for (int i = 0; i < 4; i++)
#pragma unroll
        for (int j = 0; j < 8; j++) { acc1[i][j] = 0.0f; acc2[i][j] = 0.0f; }

    for (int kc = 0; kc < 128; kc += KC) {
        __syncthreads();
        // stage X^T chunk: xsT[kk][n] = X[gn0+n][kc+kk]
#pragma unroll
        for (int it = 0; it < XLD; it++) {
            int idx = tid + 256 * it;
            int n = idx / KPF, k4 = idx % KPF;
            float4 v = make_float4(0.f, 0.f, 0.f, 0.f);
            if (gn0 + n < N) v = *(const float4*)&X[(size_t)(gn0 + n) * 128 + kc + k4 * 4];
            xsT[k4 * 4 + 0][n] = v.x;
            xsT[k4 * 4 + 1][n] = v.y;
            xsT[k4 * 4 + 2][n] = v.z;
            xsT[k4 * 4 + 3][n] = v.w;
        }
        // stage both W^T chunks: wt[kk][d] = W[d][kc+kk]
#pragma unroll
        for (int it = 0; it < WLD; it++) {
            int idx = tid + 256 * it;
            int d = idx / KPF, k4 = idx % KPF;
            float4 v = *(const float4*)&W1[(size_t)d * 128 + kc + k4 * 4];
            wt1[k4 * 4 + 0][d] = v.x;
            wt1[k4 * 4 + 1][d] = v.y;
            wt1[k4 * 4 + 2][d] = v.z;
            wt1[k4 * 4 + 3][d] = v.w;
        }
#pragma unroll
        for (int it = 0; it < WLD; it++) {
            int idx = tid + 256 * it;
            int d = idx / KPF, k4 = idx % KPF;
            float4 v = *(const float4*)&W2[(size_t)d * 128 + kc + k4 * 4];
            wt2[k4 * 4 + 0][d] = v.x;
            wt2[k4 * 4 + 1][d] = v.y;
            wt2[k4 * 4 + 2][d] = v.z;
            wt2[k4 * 4 + 3][d] = v.w;
        }
        __syncthreads();
#pragma unroll
        for (int kk = 0; kk < KC; kk++) {
            float4 xv = *(const float4*)&xsT[kk][n0];
            float4 wa1 = *(const float4*)&wt1[kk][d0];
            float4 wb1 = *(const float4*)&wt1[kk][d1];
            float4 wa2 = *(const float4*)&wt2[kk][d0];
            float4 wb2 = *(const float4*)&wt2[kk][d1];
            float xa[4] = {xv.x, xv.y, xv.z, xv.w};
            float w1a[8] = {wa1.x, wa1.y, wa1.z, wa1.w, wb1.x, wb1.y, wb1.z, wb1.w};
            float w2a[8] = {wa2.x, wa2.y, wa2.z, wa2.w, wb2.x, wb2.y, wb2.z, wb2.w};
#pragma unroll
            for (int i = 0; i < 4; i++)
#pragma unroll
                for (int j = 0; j < 8; j++) {
                    acc1[i][j] += xa[i] * w1a[j];
                    acc2[i][j] += xa[i] * w2a[j];
                }
        }
    }
#pragma unroll
    for (int i = 0; i < 4; i++) {
        int n = gn0 + n0 + i;
        if (n < N) {
            *(float4*)&Y1[(size_t)n * BN + d0] =
                make_float4(acc1[i][0], acc1[i][1], acc1[i][2], acc1[i][3]);
            *(float4*)&Y1[(size_t)n * BN + d1] =
                make_float4(acc1[i][4], acc1[i][5], acc1[i][6], acc1[i][7]);
            *(float4*)&Y2[(size_t)n * BN + d0] =
                make_float4(acc2[i][0], acc2[i][1], acc2[i][2], acc2[i][3]);
            *(float4*)&Y2[(size_t)n * BN + d1] =
                make_float4(acc2[i][4], acc2[i][5], acc2[i][6], acc2[i][7]);
        }
    }
}

// ---------------- aggregation: one wave per dst node ----------------
// hio holds xr on entry (written by k_gemm_dual), h on exit (in place;
// each wave reads only its own row before writing it). NOT __restrict__.

__global__ __launch_bounds__(256) void k_agg1(const float* __restrict__ xl,
                                              float* hio,
                                              const int* __restrict__ offs,
                                              const int* __restrict__ csr_s,
                                              const float* __restrict__ csr_w,
                                              const float* __restrict__ bias) {
    int wid = (blockIdx.x * 256 + threadIdx.x) >> 6;
    int lane = threadIdx.x & 63;
    if (wid >= NN) return;
    int s0 = offs[wid], s1 = offs[wid + 1];
    float a0 = 0.f, a1 = 0.f, c0 = 0.f, c1 = 0.f;
    int e = s0;
    for (; e + 2 <= s1; e += 2) {
        int sA = csr_s[e], sB = csr_s[e + 1];
        float wA = csr_w[e], wB = csr_w[e + 1];
        float2 vA = *(const float2*)&xl[(size_t)sA * 128 + lane * 2];
        float2 vB = *(const float2*)&xl[(size_t)sB * 128 + lane * 2];
        a0 += wA * vA.x; a1 += wA * vA.y;
        c0 += wB * vB.x; c1 += wB * vB.y;
    }
    if (e < s1) {
        int sA = csr_s[e];
        float wA = csr_w[e];
        float2 vA = *(const float2*)&xl[(size_t)sA * 128 + lane * 2];
        a0 += wA * vA.x; a1 += wA * vA.y;
    }
    a0 += c0; a1 += c1;
    float inv = 1.0f / fmaxf((float)(s1 - s0), 1.0f);
    float2 r = *(const float2*)&hio[(size_t)wid * 128 + lane * 2];
    float o0 = fmaxf(a0 * inv + bias[lane * 2 + 0] + r.x, 0.0f);
    float o1 = fmaxf(a1 * inv + bias[lane * 2 + 1] + r.y, 0.0f);
    *(float2*)&hio[(size_t)wid * 128 + lane * 2] = make_float2(o0, o1);
}

// oio holds hr on entry, logits on exit (in place, same row-exclusive pattern)
__global__ __launch_bounds__(256) void k_agg2(const float* __restrict__ hl,
                                              float* oio,
                                              const int* __restrict__ offs,
                                              const int* __restrict__ csr_s,
                                              const float* __restrict__ csr_w,
                                              const float* __restrict__ bias) {
    int wid = (blockIdx.x * 256 + threadIdx.x) >> 6;
    int lane = threadIdx.x & 63;
    if (wid >= NN) return;
    int s0 = offs[wid], s1 = offs[wid + 1];
    float a = 0.f, c = 0.f;
    int e = s0;
    for (; e + 2 <= s1; e += 2) {
        int sA = csr_s[e], sB = csr_s[e + 1];
        float wA = csr_w[e], wB = csr_w[e + 1];
        a += wA * hl[(size_t)sA * 64 + lane];
        c += wB * hl[(size_t)sB * 64 + lane];
    }
    if (e < s1) {
        a += csr_w[e] * hl[(size_t)csr_s[e] * 64 + lane];
    }
    a += c;
    float inv = 1.0f / fmaxf((float)(s1 - s0), 1.0f);
    oio[(size_t)wid * 64 + lane] =
        a * inv + bias[lane] + oio[(size_t)wid * 64 + lane];
}

// ---------------- launch ----------------

extern "C" void kernel_launch(void* const* d_in, const int* in_sizes, int n_in,
                              void* d_out, int out_size, void* d_ws, size_t ws_size,
                              hipStream_t stream) {
    const float* x   = (const float*)d_in[0];
    const int*   ei  = (const int*)d_in[1];   // [2][NE] int32 (harness: integer -> int*)
    const float* ew  = (const float*)d_in[2];
    const float* Wl1 = (const float*)d_in[3];
    const float* bl1 = (const float*)d_in[4];
    const float* Wr1 = (const float*)d_in[5];
    const float* Wl2 = (const float*)d_in[6];
    const float* bl2 = (const float*)d_in[7];
    const float* Wr2 = (const float*)d_in[8];

    float* h      = (float*)d_out;                  // [NN][128]
    float* logits = h + (size_t)NN * 128;           // [NN][64]

    char* w = (char*)d_ws;
    size_t p = 0;
    auto alloc = [&](size_t bytes) {
        size_t o = p;
        p += (bytes + 255) & ~(size_t)255;
        return o;
    };
    int*   cnt    = (int*)(w + alloc((size_t)NN * 4));
    int*   incl   = (int*)(w + alloc((size_t)NN * 4));
    int*   bsum   = (int*)(w + alloc(4096));
    int*   offs   = (int*)(w + alloc((size_t)(NN + 1) * 4));
    int*   cursor = (int*)(w + alloc((size_t)NN * 4));
    int*   csr_s  = (int*)(w + alloc((size_t)NE * 4));
    float* csr_w  = (float*)(w + alloc((size_t)NE * 4));
    float* xl     = (float*)(w + alloc((size_t)NN * 128 * 4));  // layer-2 hl reuses this
    float* hl = xl;
    // total ws use: ~78.4 MB

    const int* e_src = ei;
    const int* e_dst = ei + NE;

    int nsb = (NN + 1023) / 1024;  // 98 scan blocks

    hipMemsetAsync(cnt, 0, (size_t)NN * 4, stream);
    k_hist<<<4096, 256, 0, stream>>>(e_dst, cnt);
    k_scan_block<<<nsb, 1024, 0, stream>>>(cnt, incl, bsum, NN);
    k_scan_bsum<<<1, 128, 0, stream>>>(bsum, nsb);
    k_offs<<<(NN + 255) / 256, 256, 0, stream>>>(incl, bsum, offs, NN);
    hipMemcpyAsync(cursor, offs, (size_t)NN * 4, hipMemcpyDeviceToDevice, stream);
    k_fill<<<4096, 256, 0, stream>>>(e_src, e_dst, ew, cursor, csr_s, csr_w);

    // layer 1: xl -> ws, xr -> h (d_out), then in-place aggregate+epilogue
    k_gemm_dual<64, 128, 32><<<(NN + 63) / 64, 256, 0, stream>>>(x, Wl1, Wr1, xl, h, NN);
    k_agg1<<<(NN + 3) / 4, 256, 0, stream>>>(xl, h, offs, csr_s, csr_w, bl1);

    // layer 2: hl -> ws (reuse), hr -> logits (d_out), in-place aggregate
    k_gemm_dual<128, 64, 32><<<(NN + 127) / 128, 256, 0, stream>>>(h, Wl2, Wr2, hl, logits, NN);
    k_agg2<<<(NN + 3) / 4, 256, 0, stream>>>(hl, logits, offs, csr_s, csr_w, bl2);
}

// Round 3
// 804.166 us; speedup vs baseline: 1.3537x; 1.3537x over previous
//
#include <hip/hip_runtime.h>
#include <hip/hip_bf16.h>

#define NN 100000
#define NE 3200000
// D_IN = D_HID = 128, D_OUT = 64

// bf16 (stored as uint packed pair) -> f32 expansion: low/high halves
__device__ inline float blo(unsigned int u) { return __uint_as_float(u << 16); }
__device__ inline float bhi(unsigned int u) { return __uint_as_float(u & 0xffff0000u); }

__device__ inline unsigned short f2bs(float f) {
    __hip_bfloat16 b = __float2bfloat16(f);
    return __builtin_bit_cast(unsigned short, b);
}

// ---------------- CSR build ----------------

__global__ void k_hist(const int* __restrict__ dst, int* __restrict__ cnt) {
    int stride = gridDim.x * blockDim.x;
    for (int i = blockIdx.x * blockDim.x + threadIdx.x; i < NE; i += stride)
        atomicAdd(&cnt[dst[i]], 1);
}

__global__ __launch_bounds__(1024) void k_scan_block(const int* __restrict__ cnt,
                                                     int* __restrict__ incl,
                                                     int* __restrict__ bsum, int n) {
    __shared__ int s[1024];
    int t = threadIdx.x, i = blockIdx.x * 1024 + t;
    int v = (i < n) ? cnt[i] : 0;
    s[t] = v; __syncthreads();
    for (int off = 1; off < 1024; off <<= 1) {
        int x = (t >= off) ? s[t - off] : 0;
        __syncthreads();
        s[t] += x;
        __syncthreads();
    }
    if (i < n) incl[i] = s[t];
    if (t == 1023) bsum[blockIdx.x] = s[t];
}

__global__ void k_scan_bsum(int* __restrict__ bsum, int nb) {
    __shared__ int s[128];
    int t = threadIdx.x;
    int v = (t < nb) ? bsum[t] : 0;
    s[t] = v; __syncthreads();
    for (int off = 1; off < 128; off <<= 1) {
        int x = (t >= off) ? s[t - off] : 0;
        __syncthreads();
        s[t] += x;
        __syncthreads();
    }
    if (t < nb) bsum[t] = s[t] - v;  // exclusive
}

// offs[i+1] = incl[i] + bsum[blk]; cursor[i] = offs[i] (fused, no memcpy)
__global__ void k_offs(const int* __restrict__ incl, const int* __restrict__ bsum,
                       const int* __restrict__ cnt, int* __restrict__ offs,
                       int* __restrict__ cursor, int n) {
    int i = blockIdx.x * blockDim.x + threadIdx.x;
    if (i < n) {
        int v = incl[i] + bsum[i >> 10];
        offs[i + 1] = v;
        cursor[i] = v - cnt[i];
    }
    if (i == 0) offs[0] = 0;
}

__global__ void k_fill(const int* __restrict__ src, const int* __restrict__ dst,
                       const float* __restrict__ ew, int* __restrict__ cursor,
                       int2* __restrict__ csr) {
    int stride = gridDim.x * blockDim.x;
    for (int i = blockIdx.x * blockDim.x + threadIdx.x; i < NE; i += stride) {
        int d = dst[i];
        int p = atomicAdd(&cursor[d], 1);
        csr[p] = make_int2(src[i], __float_as_int(ew[i]));
    }
}

// ---------------- fused dual f32 GEMM ----------------
// Y1 (bf16) = X @ W1^T ; Y2 (f32) = X @ W2^T. 256 thr; 4 nodes x 8 dims each.

template <int BM, int BN, int KC>
__global__ __launch_bounds__(256) void k_gemm_dual(const float* __restrict__ X,
                                                   const float* __restrict__ W1,
                                                   const float* __restrict__ W2,
                                                   unsigned short* __restrict__ Y1b,
                                                   float* __restrict__ Y2, int N) {
    constexpr int TD = BN / 8;
    constexpr int TN = 256 / TD;
    static_assert(BM / TN == 4, "4 nodes per thread");
    constexpr int KPF = KC / 4;
    constexpr int XLD = BM * KC / (4 * 256);
    constexpr int WLD = BN * KC / (4 * 256);
    static_assert(XLD * 4 * 256 == BM * KC && WLD * 4 * 256 == BN * KC);

    __shared__ float xsT[KC][BM + 4];
    __shared__ float wt1[KC][BN + 4];
    __shared__ float wt2[KC][BN + 4];

    const int tid = threadIdx.x;
    const int td = tid % TD, tn = tid / TD;
    const int n0 = tn * 4;
    const int d0 = td * 4;
    const int d1 = BN / 2 + td * 4;
    const int gn0 = blockIdx.x * BM;

    float acc1[4][8], acc2[4][8];
#pragma unroll
    for (int i = 0; i < 4; i++)
#pragma unroll
        for (int j = 0; j < 8; j++) { acc1[i][j] = 0.0f; acc2[i][j] = 0.0f; }

    for (int kc = 0; kc < 128; kc += KC) {
        __syncthreads();
#pragma unroll
        for (int it = 0; it < XLD; it++) {
            int idx = tid + 256 * it;
            int n = idx / KPF, k4 = idx % KPF;
            float4 v = make_float4(0.f, 0.f, 0.f, 0.f);
            if (gn0 + n < N) v = *(const float4*)&X[(size_t)(gn0 + n) * 128 + kc + k4 * 4];
            xsT[k4 * 4 + 0][n] = v.x;
            xsT[k4 * 4 + 1][n] = v.y;
            xsT[k4 * 4 + 2][n] = v.z;
            xsT[k4 * 4 + 3][n] = v.w;
        }
#pragma unroll
        for (int it = 0; it < WLD; it++) {
            int idx = tid + 256 * it;
            int d = idx / KPF, k4 = idx % KPF;
            float4 v = *(const float4*)&W1[(size_t)d * 128 + kc + k4 * 4];
            wt1[k4 * 4 + 0][d] = v.x;
            wt1[k4 * 4 + 1][d] = v.y;
            wt1[k4 * 4 + 2][d] = v.z;
            wt1[k4 * 4 + 3][d] = v.w;
        }
#pragma unroll
        for (int it = 0; it < WLD; it++) {
            int idx = tid + 256 * it;
            int d = idx / KPF, k4 = idx % KPF;
            float4 v = *(const float4*)&W2[(size_t)d * 128 + kc + k4 * 4];
            wt2[k4 * 4 + 0][d] = v.x;
            wt2[k4 * 4 + 1][d] = v.y;
            wt2[k4 * 4 + 2][d] = v.z;
            wt2[k4 * 4 + 3][d] = v.w;
        }
        __syncthreads();
#pragma unroll
        for (int kk = 0; kk < KC; kk++) {
            float4 xv = *(const float4*)&xsT[kk][n0];
            float4 wa1 = *(const float4*)&wt1[kk][d0];
            float4 wb1 = *(const float4*)&wt1[kk][d1];
            float4 wa2 = *(const float4*)&wt2[kk][d0];
            float4 wb2 = *(const float4*)&wt2[kk][d1];
            float xa[4] = {xv.x, xv.y, xv.z, xv.w};
            float w1a[8] = {wa1.x, wa1.y, wa1.z, wa1.w, wb1.x, wb1.y, wb1.z, wb1.w};
            float w2a[8] = {wa2.x, wa2.y, wa2.z, wa2.w, wb2.x, wb2.y, wb2.z, wb2.w};
#pragma unroll
            for (int i = 0; i < 4; i++)
#pragma unroll
                for (int j = 0; j < 8; j++) {
                    acc1[i][j] += xa[i] * w1a[j];
                    acc2[i][j] += xa[i] * w2a[j];
                }
        }
    }
#pragma unroll
    for (int i = 0; i < 4; i++) {
        int n = gn0 + n0 + i;
        if (n < N) {
            ushort4 sA, sB;
            sA.x = f2bs(acc1[i][0]); sA.y = f2bs(acc1[i][1]);
            sA.z = f2bs(acc1[i][2]); sA.w = f2bs(acc1[i][3]);
            sB.x = f2bs(acc1[i][4]); sB.y = f2bs(acc1[i][5]);
            sB.z = f2bs(acc1[i][6]); sB.w = f2bs(acc1[i][7]);
            *(ushort4*)&Y1b[(size_t)n * BN + d0] = sA;
            *(ushort4*)&Y1b[(size_t)n * BN + d1] = sB;
            *(float4*)&Y2[(size_t)n * BN + d0] =
                make_float4(acc2[i][0], acc2[i][1], acc2[i][2], acc2[i][3]);
            *(float4*)&Y2[(size_t)n * BN + d1] =
                make_float4(acc2[i][4], acc2[i][5], acc2[i][6], acc2[i][7]);
        }
    }
}

// ---------------- aggregation ----------------
// layer 1: one wave per dst; bf16 rows (256B), lane covers dims 2l,2l+1; unroll 4.
// hio: xr on entry, h on exit (row-exclusive in-place).
__global__ __launch_bounds__(256) void k_agg1(const unsigned int* __restrict__ xl32,
                                              float* hio,
                                              const int* __restrict__ offs,
                                              const int2* __restrict__ csr,
                                              const float* __restrict__ bias) {
    int wid = (blockIdx.x * 256 + threadIdx.x) >> 6;
    int lane = threadIdx.x & 63;
    if (wid >= NN) return;
    int s0 = offs[wid], s1 = offs[wid + 1];
    float a0 = 0.f, a1 = 0.f, b0 = 0.f, b1 = 0.f;
    float c0 = 0.f, c1 = 0.f, d0 = 0.f, d1 = 0.f;
    int e = s0;
    for (; e + 4 <= s1; e += 4) {
        int2 cA = csr[e], cB = csr[e + 1], cC = csr[e + 2], cD = csr[e + 3];
        unsigned int rA = xl32[(size_t)cA.x * 64 + lane];
        unsigned int rB = xl32[(size_t)cB.x * 64 + lane];
        unsigned int rC = xl32[(size_t)cC.x * 64 + lane];
        unsigned int rD = xl32[(size_t)cD.x * 64 + lane];
        float wA = __int_as_float(cA.y), wB = __int_as_float(cB.y);
        float wC = __int_as_float(cC.y), wD = __int_as_float(cD.y);
        a0 += wA * blo(rA); a1 += wA * bhi(rA);
        b0 += wB * blo(rB); b1 += wB * bhi(rB);
        c0 += wC * blo(rC); c1 += wC * bhi(rC);
        d0 += wD * blo(rD); d1 += wD * bhi(rD);
    }
    for (; e < s1; ++e) {
        int2 cA = csr[e];
        unsigned int rA = xl32[(size_t)cA.x * 64 + lane];
        float wA = __int_as_float(cA.y);
        a0 += wA * blo(rA); a1 += wA * bhi(rA);
    }
    a0 += b0 + c0 + d0; a1 += b1 + c1 + d1;
    float inv = 1.0f / fmaxf((float)(s1 - s0), 1.0f);
    float2 bz = *(const float2*)&bias[2 * lane];
    float2 r = *(const float2*)&hio[(size_t)wid * 128 + 2 * lane];
    float o0 = fmaxf(a0 * inv + bz.x + r.x, 0.0f);
    float o1 = fmaxf(a1 * inv + bz.y + r.y, 0.0f);
    *(float2*)&hio[(size_t)wid * 128 + 2 * lane] = make_float2(o0, o1);
}

// layer 2: bf16 rows (128B = half wave). Two 32-lane halves process alternate
// edges; combine via shfl_xor(32). oio: hr on entry, logits on exit.
__global__ __launch_bounds__(256) void k_agg2(const unsigned int* __restrict__ hl32,
                                              float* oio,
                                              const int* __restrict__ offs,
                                              const int2* __restrict__ csr,
                                              const float* __restrict__ bias) {
    int wid = (blockIdx.x * 256 + threadIdx.x) >> 6;
    int lane = threadIdx.x & 63;
    if (wid >= NN) return;
    int s0 = offs[wid], s1 = offs[wid + 1];
    int half = lane >> 5, sl = lane & 31;
    float a0 = 0.f, a1 = 0.f, b0 = 0.f, b1 = 0.f;
    int e = s0 + half;
    for (; e + 2 < s1; e += 4) {
        int2 cA = csr[e], cB = csr[e + 2];
        unsigned int rA = hl32[(size_t)cA.x * 32 + sl];
        unsigned int rB = hl32[(size_t)cB.x * 32 + sl];
        float wA = __int_as_float(cA.y), wB = __int_as_float(cB.y);
        a0 += wA * blo(rA); a1 += wA * bhi(rA);
        b0 += wB * blo(rB); b1 += wB * bhi(rB);
    }
    if (e < s1) {
        int2 cA = csr[e];
        unsigned int rA = hl32[(size_t)cA.x * 32 + sl];
        float wA = __int_as_float(cA.y);
        a0 += wA * blo(rA); a1 += wA * bhi(rA);
    }
    a0 += b0; a1 += b1;
    a0 += __shfl_xor(a0, 32);
    a1 += __shfl_xor(a1, 32);
    if (half == 0) {
        float inv = 1.0f / fmaxf((float)(s1 - s0), 1.0f);
        float2 bz = *(const float2*)&bias[2 * sl];
        float2 r = *(const float2*)&oio[(size_t)wid * 64 + 2 * sl];
        *(float2*)&oio[(size_t)wid * 64 + 2 * sl] =
            make_float2(a0 * inv + bz.x + r.x, a1 * inv + bz.y + r.y);
    }
}

// ---------------- launch ----------------

extern "C" void kernel_launch(void* const* d_in, const int* in_sizes, int n_in,
                              void* d_out, int out_size, void* d_ws, size_t ws_size,
                              hipStream_t stream) {
    const float* x   = (const float*)d_in[0];
    const int*   ei  = (const int*)d_in[1];   // [2][NE] int32
    const float* ew  = (const float*)d_in[2];
    const float* Wl1 = (const float*)d_in[3];
    const float* bl1 = (const float*)d_in[4];
    const float* Wr1 = (const float*)d_in[5];
    const float* Wl2 = (const float*)d_in[6];
    const float* bl2 = (const float*)d_in[7];
    const float* Wr2 = (const float*)d_in[8];

    float* h      = (float*)d_out;                  // [NN][128]
    float* logits = h + (size_t)NN * 128;           // [NN][64]

    char* w = (char*)d_ws;
    size_t p = 0;
    auto alloc = [&](size_t bytes) {
        size_t o = p;
        p += (bytes + 255) & ~(size_t)255;
        return o;
    };
    int*   cnt    = (int*)(w + alloc((size_t)NN * 4));
    int*   incl   = (int*)(w + alloc((size_t)NN * 4));
    int*   bsum   = (int*)(w + alloc(4096));
    int*   offs   = (int*)(w + alloc((size_t)(NN + 1) * 4));
    int*   cursor = (int*)(w + alloc((size_t)NN * 4));
    int2*  csr    = (int2*)(w + alloc((size_t)NE * 8));
    unsigned short* xlb = (unsigned short*)(w + alloc((size_t)NN * 128 * 2));
    unsigned short* hlb = xlb;  // layer-2 reuse (dead after k_agg1)
    // total ws use: ~53 MB

    const int* e_src = ei;
    const int* e_dst = ei + NE;

    int nsb = (NN + 1023) / 1024;  // 98 scan blocks

    hipMemsetAsync(cnt, 0, (size_t)NN * 4, stream);
    k_hist<<<4096, 256, 0, stream>>>(e_dst, cnt);
    k_scan_block<<<nsb, 1024, 0, stream>>>(cnt, incl, bsum, NN);
    k_scan_bsum<<<1, 128, 0, stream>>>(bsum, nsb);
    k_offs<<<(NN + 255) / 256, 256, 0, stream>>>(incl, bsum, cnt, offs, cursor, NN);
    k_fill<<<4096, 256, 0, stream>>>(e_src, e_dst, ew, cursor, csr);

    // layer 1: xl (bf16) -> ws, xr (f32) -> h (d_out), in-place aggregate
    k_gemm_dual<64, 128, 32><<<(NN + 63) / 64, 256, 0, stream>>>(x, Wl1, Wr1, xlb, h, NN);
    k_agg1<<<(NN + 3) / 4, 256, 0, stream>>>((const unsigned int*)xlb, h, offs, csr, bl1);

    // layer 2: hl (bf16) -> ws, hr (f32) -> logits, in-place aggregate
    k_gemm_dual<128, 64, 32><<<(NN + 127) / 128, 256, 0, stream>>>(h, Wl2, Wr2, hlb, logits, NN);
    k_agg2<<<(NN + 3) / 4, 256, 0, stream>>>((const unsigned int*)hlb, logits, offs, csr, bl2);
}

// Round 5
// 727.616 us; speedup vs baseline: 1.4961x; 1.1052x over previous
//
#include <hip/hip_runtime.h>
#include <hip/hip_bf16.h>

#define NN 100000
#define NE 3200000
// D_IN = D_HID = 128, D_OUT = 64

// bf16 (stored as uint packed pair) -> f32 expansion: low/high halves
__device__ inline float blo(unsigned int u) { return __uint_as_float(u << 16); }
__device__ inline float bhi(unsigned int u) { return __uint_as_float(u & 0xffff0000u); }

__device__ inline unsigned short f2bs(float f) {
    __hip_bfloat16 b = __float2bfloat16(f);
    return __builtin_bit_cast(unsigned short, b);
}

// ---------------- CSR build ----------------

// rank[i] = arrival index of edge i within its destination's segment.
// One edge per thread (NE = 12500 * 256 exactly).
__global__ void k_hist_rank(const int* __restrict__ dst, int* __restrict__ cnt,
                            int* __restrict__ rank) {
    int i = blockIdx.x * blockDim.x + threadIdx.x;
    rank[i] = atomicAdd(&cnt[dst[i]], 1);
}

__global__ __launch_bounds__(1024) void k_scan_block(const int* __restrict__ cnt,
                                                     int* __restrict__ incl,
                                                     int* __restrict__ bsum, int n) {
    __shared__ int s[1024];
    int t = threadIdx.x, i = blockIdx.x * 1024 + t;
    int v = (i < n) ? cnt[i] : 0;
    s[t] = v; __syncthreads();
    for (int off = 1; off < 1024; off <<= 1) {
        int x = (t >= off) ? s[t - off] : 0;
        __syncthreads();
        s[t] += x;
        __syncthreads();
    }
    if (i < n) incl[i] = s[t];
    if (t == 1023) bsum[blockIdx.x] = s[t];
}

__global__ void k_scan_bsum(int* __restrict__ bsum, int nb) {
    __shared__ int s[128];
    int t = threadIdx.x;
    int v = (t < nb) ? bsum[t] : 0;
    s[t] = v; __syncthreads();
    for (int off = 1; off < 128; off <<= 1) {
        int x = (t >= off) ? s[t - off] : 0;
        __syncthreads();
        s[t] += x;
        __syncthreads();
    }
    if (t < nb) bsum[t] = s[t] - v;  // exclusive
}

__global__ void k_offs(const int* __restrict__ incl, const int* __restrict__ bsum,
                       int* __restrict__ offs, int n) {
    int i = blockIdx.x * blockDim.x + threadIdx.x;
    if (i < n) offs[i + 1] = incl[i] + bsum[i >> 10];
    if (i == 0) offs[0] = 0;
}

// Atomic-free placement: position = offs[dst] + rank. One edge per thread.
__global__ void k_place(const int* __restrict__ src, const int* __restrict__ dst,
                        const float* __restrict__ ew, const int* __restrict__ offs,
                        const int* __restrict__ rank, int2* __restrict__ csr) {
    int i = blockIdx.x * blockDim.x + threadIdx.x;
    int p = offs[dst[i]] + rank[i];
    csr[p] = make_int2(src[i], __float_as_int(ew[i]));
}

// ---------------- fused dual f32 GEMM ----------------
// Y1 (bf16) = X @ W1^T ; Y2 (f32) = X @ W2^T. 256 thr; 4 nodes x 8 dims each.

template <int BM, int BN, int KC>
__global__ __launch_bounds__(256) void k_gemm_dual(const float* __restrict__ X,
                                                   const float* __restrict__ W1,
                                                   const float* __restrict__ W2,
                                                   unsigned short* __restrict__ Y1b,
                                                   float* __restrict__ Y2, int N) {
    constexpr int TD = BN / 8;
    constexpr int TN = 256 / TD;
    static_assert(BM / TN == 4, "4 nodes per thread");
    constexpr int KPF = KC / 4;
    constexpr int XLD = BM * KC / (4 * 256);
    constexpr int WLD = BN * KC / (4 * 256);
    static_assert(XLD * 4 * 256 == BM * KC && WLD * 4 * 256 == BN * KC);

    __shared__ float xsT[KC][BM + 4];
    __shared__ float wt1[KC][BN + 4];
    __shared__ float wt2[KC][BN + 4];

    const int tid = threadIdx.x;
    const int td = tid % TD, tn = tid / TD;
    const int n0 = tn * 4;
    const int d0 = td * 4;
    const int d1 = BN / 2 + td * 4;
    const int gn0 = blockIdx.x * BM;

    float acc1[4][8], acc2[4][8];
#pragma unroll
    for (int i = 0; i < 4; i++)
#pragma unroll
        for (int j = 0; j < 8; j++) { acc1[i][j] = 0.0f; acc2[i][j] = 0.0f; }

    for (int kc = 0; kc < 128; kc += KC) {
        __syncthreads();
#pragma unroll
        for (int it = 0; it < XLD; it++) {
            int idx = tid + 256 * it;
            int n = idx / KPF, k4 = idx % KPF;
            float4 v = make_float4(0.f, 0.f, 0.f, 0.f);
            if (gn0 + n < N) v = *(const float4*)&X[(size_t)(gn0 + n) * 128 + kc + k4 * 4];
            xsT[k4 * 4 + 0][n] = v.x;
            xsT[k4 * 4 + 1][n] = v.y;
            xsT[k4 * 4 + 2][n] = v.z;
            xsT[k4 * 4 + 3][n] = v.w;
        }
#pragma unroll
        for (int it = 0; it < WLD; it++) {
            int idx = tid + 256 * it;
            int d = idx / KPF, k4 = idx % KPF;
            float4 v = *(const float4*)&W1[(size_t)d * 128 + kc + k4 * 4];
            wt1[k4 * 4 + 0][d] = v.x;
            wt1[k4 * 4 + 1][d] = v.y;
            wt1[k4 * 4 + 2][d] = v.z;
            wt1[k4 * 4 + 3][d] = v.w;
        }
#pragma unroll
        for (int it = 0; it < WLD; it++) {
            int idx = tid + 256 * it;
            int d = idx / KPF, k4 = idx % KPF;
            float4 v = *(const float4*)&W2[(size_t)d * 128 + kc + k4 * 4];
            wt2[k4 * 4 + 0][d] = v.x;
            wt2[k4 * 4 + 1][d] = v.y;
            wt2[k4 * 4 + 2][d] = v.z;
            wt2[k4 * 4 + 3][d] = v.w;
        }
        __syncthreads();
#pragma unroll
        for (int kk = 0; kk < KC; kk++) {
            float4 xv = *(const float4*)&xsT[kk][n0];
            float4 wa1 = *(const float4*)&wt1[kk][d0];
            float4 wb1 = *(const float4*)&wt1[kk][d1];
            float4 wa2 = *(const float4*)&wt2[kk][d0];
            float4 wb2 = *(const float4*)&wt2[kk][d1];
            float xa[4] = {xv.x, xv.y, xv.z, xv.w};
            float w1a[8] = {wa1.x, wa1.y, wa1.z, wa1.w, wb1.x, wb1.y, wb1.z, wb1.w};
            float w2a[8] = {wa2.x, wa2.y, wa2.z, wa2.w, wb2.x, wb2.y, wb2.z, wb2.w};
#pragma unroll
            for (int i = 0; i < 4; i++)
#pragma unroll
                for (int j = 0; j < 8; j++) {
                    acc1[i][j] += xa[i] * w1a[j];
                    acc2[i][j] += xa[i] * w2a[j];
                }
        }
    }
#pragma unroll
    for (int i = 0; i < 4; i++) {
        int n = gn0 + n0 + i;
        if (n < N) {
            ushort4 sA, sB;
            sA.x = f2bs(acc1[i][0]); sA.y = f2bs(acc1[i][1]);
            sA.z = f2bs(acc1[i][2]); sA.w = f2bs(acc1[i][3]);
            sB.x = f2bs(acc1[i][4]); sB.y = f2bs(acc1[i][5]);
            sB.z = f2bs(acc1[i][6]); sB.w = f2bs(acc1[i][7]);
            *(ushort4*)&Y1b[(size_t)n * BN + d0] = sA;
            *(ushort4*)&Y1b[(size_t)n * BN + d1] = sB;
            *(float4*)&Y2[(size_t)n * BN + d0] =
                make_float4(acc2[i][0], acc2[i][1], acc2[i][2], acc2[i][3]);
            *(float4*)&Y2[(size_t)n * BN + d1] =
                make_float4(acc2[i][4], acc2[i][5], acc2[i][6], acc2[i][7]);
        }
    }
}

// ---------------- aggregation ----------------
// layer 1: one wave per dst; bf16 rows (256B), lane covers dims 2l,2l+1; unroll 4.
// hio: xr on entry, h on exit (row-exclusive in-place).
__global__ __launch_bounds__(256) void k_agg1(const unsigned int* __restrict__ xl32,
                                              float* hio,
                                              const int* __restrict__ offs,
                                              const int2* __restrict__ csr,
                                              const float* __restrict__ bias) {
    int wid = (blockIdx.x * 256 + threadIdx.x) >> 6;
    int lane = threadIdx.x & 63;
    if (wid >= NN) return;
    int s0 = offs[wid], s1 = offs[wid + 1];
    float a0 = 0.f, a1 = 0.f, b0 = 0.f, b1 = 0.f;
    float c0 = 0.f, c1 = 0.f, d0 = 0.f, d1 = 0.f;
    int e = s0;
    for (; e + 4 <= s1; e += 4) {
        int2 cA = csr[e], cB = csr[e + 1], cC = csr[e + 2], cD = csr[e + 3];
        unsigned int rA = xl32[(size_t)cA.x * 64 + lane];
        unsigned int rB = xl32[(size_t)cB.x * 64 + lane];
        unsigned int rC = xl32[(size_t)cC.x * 64 + lane];
        unsigned int rD = xl32[(size_t)cD.x * 64 + lane];
        float wA = __int_as_float(cA.y), wB = __int_as_float(cB.y);
        float wC = __int_as_float(cC.y), wD = __int_as_float(cD.y);
        a0 += wA * blo(rA); a1 += wA * bhi(rA);
        b0 += wB * blo(rB); b1 += wB * bhi(rB);
        c0 += wC * blo(rC); c1 += wC * bhi(rC);
        d0 += wD * blo(rD); d1 += wD * bhi(rD);
    }
    for (; e < s1; ++e) {
        int2 cA = csr[e];
        unsigned int rA = xl32[(size_t)cA.x * 64 + lane];
        float wA = __int_as_float(cA.y);
        a0 += wA * blo(rA); a1 += wA * bhi(rA);
    }
    a0 += b0 + c0 + d0; a1 += b1 + c1 + d1;
    float inv = 1.0f / fmaxf((float)(s1 - s0), 1.0f);
    float2 bz = *(const float2*)&bias[2 * lane];
    float2 r = *(const float2*)&hio[(size_t)wid * 128 + 2 * lane];
    float o0 = fmaxf(a0 * inv + bz.x + r.x, 0.0f);
    float o1 = fmaxf(a1 * inv + bz.y + r.y, 0.0f);
    *(float2*)&hio[(size_t)wid * 128 + 2 * lane] = make_float2(o0, o1);
}

// layer 2: bf16 rows (128B = half wave). Two 32-lane halves process alternate
// edges; combine via shfl_xor(32). oio: hr on entry, logits on exit.
__global__ __launch_bounds__(256) void k_agg2(const unsigned int* __restrict__ hl32,
                                              float* oio,
                                              const int* __restrict__ offs,
                                              const int2* __restrict__ csr,
                                              const float* __restrict__ bias) {
    int wid = (blockIdx.x * 256 + threadIdx.x) >> 6;
    int lane = threadIdx.x & 63;
    if (wid >= NN) return;
    int s0 = offs[wid], s1 = offs[wid + 1];
    int half = lane >> 5, sl = lane & 31;
    float a0 = 0.f, a1 = 0.f, b0 = 0.f, b1 = 0.f;
    int e = s0 + half;
    for (; e + 2 < s1; e += 4) {
        int2 cA = csr[e], cB = csr[e + 2];
        unsigned int rA = hl32[(size_t)cA.x * 32 + sl];
        unsigned int rB = hl32[(size_t)cB.x * 32 + sl];
        float wA = __int_as_float(cA.y), wB = __int_as_float(cB.y);
        a0 += wA * blo(rA); a1 += wA * bhi(rA);
        b0 += wB * blo(rB); b1 += wB * bhi(rB);
    }
    if (e < s1) {
        int2 cA = csr[e];
        unsigned int rA = hl32[(size_t)cA.x * 32 + sl];
        float wA = __int_as_float(cA.y);
        a0 += wA * blo(rA); a1 += wA * bhi(rA);
    }
    a0 += b0; a1 += b1;
    a0 += __shfl_xor(a0, 32);
    a1 += __shfl_xor(a1, 32);
    if (half == 0) {
        float inv = 1.0f / fmaxf((float)(s1 - s0), 1.0f);
        float2 bz = *(const float2*)&bias[2 * sl];
        float2 r = *(const float2*)&oio[(size_t)wid * 64 + 2 * sl];
        *(float2*)&oio[(size_t)wid * 64 + 2 * sl] =
            make_float2(a0 * inv + bz.x + r.x, a1 * inv + bz.y + r.y);
    }
}

// ---------------- launch ----------------

extern "C" void kernel_launch(void* const* d_in, const int* in_sizes, int n_in,
                              void* d_out, int out_size, void* d_ws, size_t ws_size,
                              hipStream_t stream) {
    const float* x   = (const float*)d_in[0];
    const int*   ei  = (const int*)d_in[1];   // [2][NE] int32
    const float* ew  = (const float*)d_in[2];
    const float* Wl1 = (const float*)d_in[3];
    const float* bl1 = (const float*)d_in[4];
    const float* Wr1 = (const float*)d_in[5];
    const float* Wl2 = (const float*)d_in[6];
    const float* bl2 = (const float*)d_in[7];
    const float* Wr2 = (const float*)d_in[8];

    float* h      = (float*)d_out;                  // [NN][128]
    float* logits = h + (size_t)NN * 128;           // [NN][64]

    char* w = (char*)d_ws;
    size_t p = 0;
    auto alloc = [&](size_t bytes) {
        size_t o = p;
        p += (bytes + 255) & ~(size_t)255;
        return o;
    };
    int*   cnt    = (int*)(w + alloc((size_t)NN * 4));
    int*   incl   = (int*)(w + alloc((size_t)NN * 4));
    int*   bsum   = (int*)(w + alloc(4096));
    int*   offs   = (int*)(w + alloc((size_t)(NN + 1) * 4));
    int*   rank   = (int*)(w + alloc((size_t)NE * 4));
    int2*  csr    = (int2*)(w + alloc((size_t)NE * 8));
    unsigned short* xlb = (unsigned short*)(w + alloc((size_t)NN * 128 * 2));
    unsigned short* hlb = xlb;  // layer-2 reuse (dead after k_agg1)
    // total ws use: ~65 MB

    const int* e_src = ei;
    const int* e_dst = ei + NE;

    int nsb = (NN + 1023) / 1024;  // 98 scan blocks

    hipMemsetAsync(cnt, 0, (size_t)NN * 4, stream);
    k_hist_rank<<<NE / 256, 256, 0, stream>>>(e_dst, cnt, rank);
    k_scan_block<<<nsb, 1024, 0, stream>>>(cnt, incl, bsum, NN);
    k_scan_bsum<<<1, 128, 0, stream>>>(bsum, nsb);
    k_offs<<<(NN + 255) / 256, 256, 0, stream>>>(incl, bsum, offs, NN);
    k_place<<<NE / 256, 256, 0, stream>>>(e_src, e_dst, ew, offs, rank, csr);

    // layer 1: xl (bf16) -> ws, xr (f32) -> h (d_out), in-place aggregate
    k_gemm_dual<64, 128, 32><<<(NN + 63) / 64, 256, 0, stream>>>(x, Wl1, Wr1, xlb, h, NN);
    k_agg1<<<(NN + 3) / 4, 256, 0, stream>>>((const unsigned int*)xlb, h, offs, csr, bl1);

    // layer 2: hl (bf16) -> ws, hr (f32) -> logits, in-place aggregate
    k_gemm_dual<128, 64, 32><<<(NN + 127) / 128, 256, 0, stream>>>(h, Wl2, Wr2, hlb, logits, NN);
    k_agg2<<<(NN + 3) / 4, 256, 0, stream>>>((const unsigned int*)hlb, logits, offs, csr, bl2);
}

// Round 6
// 710.691 us; speedup vs baseline: 1.5317x; 1.0238x over previous
//
#include <hip/hip_runtime.h>
#include <hip/hip_bf16.h>

#define NN 100000
#define NE 3200000
// D_IN = D_HID = 128, D_OUT = 64

// bf16 (stored as uint packed pair) -> f32 expansion: low/high halves
__device__ inline float blo(unsigned int u) { return __uint_as_float(u << 16); }
__device__ inline float bhi(unsigned int u) { return __uint_as_float(u & 0xffff0000u); }

__device__ inline unsigned short f2bs(float f) {
    __hip_bfloat16 b = __float2bfloat16(f);
    return __builtin_bit_cast(unsigned short, b);
}

// ---------------- CSR build (non-fused pieces) ----------------

__global__ __launch_bounds__(1024) void k_scan_block(const int* __restrict__ cnt,
                                                     int* __restrict__ incl,
                                                     int* __restrict__ bsum, int n) {
    __shared__ int s[1024];
    int t = threadIdx.x, i = blockIdx.x * 1024 + t;
    int v = (i < n) ? cnt[i] : 0;
    s[t] = v; __syncthreads();
    for (int off = 1; off < 1024; off <<= 1) {
        int x = (t >= off) ? s[t - off] : 0;
        __syncthreads();
        s[t] += x;
        __syncthreads();
    }
    if (i < n) incl[i] = s[t];
    if (t == 1023) bsum[blockIdx.x] = s[t];
}

__global__ void k_scan_bsum(int* __restrict__ bsum, int nb) {
    __shared__ int s[128];
    int t = threadIdx.x;
    int v = (t < nb) ? bsum[t] : 0;
    s[t] = v; __syncthreads();
    for (int off = 1; off < 128; off <<= 1) {
        int x = (t >= off) ? s[t - off] : 0;
        __syncthreads();
        s[t] += x;
        __syncthreads();
    }
    if (t < nb) bsum[t] = s[t] - v;  // exclusive
}

__global__ void k_offs(const int* __restrict__ incl, const int* __restrict__ bsum,
                       int* __restrict__ offs, int n) {
    int i = blockIdx.x * blockDim.x + threadIdx.x;
    if (i < n) offs[i + 1] = incl[i] + bsum[i >> 10];
    if (i == 0) offs[0] = 0;
}

// Atomic-free placement: position = offs[dst] + rank. One edge per thread.
__global__ void k_place(const int* __restrict__ src, const int* __restrict__ dst,
                        const float* __restrict__ ew, const int* __restrict__ offs,
                        const int* __restrict__ rank, int2* __restrict__ csr) {
    int i = blockIdx.x * blockDim.x + threadIdx.x;
    int p = offs[dst[i]] + rank[i];
    csr[p] = make_int2(src[i], __float_as_int(ew[i]));
}

// ---------------- GEMM body (device function) ----------------
// Y1 (bf16) = X @ W1^T ; Y2 (f32) = X @ W2^T. 256 thr; 4 nodes x 8 dims each.

template <int BM, int BN, int KC>
__device__ __forceinline__ void gemm_dual_body(int bid,
                                               const float* __restrict__ X,
                                               const float* __restrict__ W1,
                                               const float* __restrict__ W2,
                                               unsigned short* __restrict__ Y1b,
                                               float* __restrict__ Y2, int N,
                                               float (*xsT)[BM + 4],
                                               float (*wt1)[BN + 4],
                                               float (*wt2)[BN + 4]) {
    constexpr int TD = BN / 8;
    constexpr int TN = 256 / TD;
    static_assert(BM / TN == 4, "4 nodes per thread");
    constexpr int KPF = KC / 4;
    constexpr int XLD = BM * KC / (4 * 256);
    constexpr int WLD = BN * KC / (4 * 256);
    static_assert(XLD * 4 * 256 == BM * KC && WLD * 4 * 256 == BN * KC);

    const int tid = threadIdx.x;
    const int td = tid % TD, tn = tid / TD;
    const int n0 = tn * 4;
    const int d0 = td * 4;
    const int d1 = BN / 2 + td * 4;
    const int gn0 = bid * BM;

    float acc1[4][8], acc2[4][8];
#pragma unroll
    for (int i = 0; i < 4; i++)
#pragma unroll
        for (int j = 0; j < 8; j++) { acc1[i][j] = 0.0f; acc2[i][j] = 0.0f; }

    for (int kc = 0; kc < 128; kc += KC) {
        __syncthreads();
#pragma unroll
        for (int it = 0; it < XLD; it++) {
            int idx = tid + 256 * it;
            int n = idx / KPF, k4 = idx % KPF;
            float4 v = make_float4(0.f, 0.f, 0.f, 0.f);
            if (gn0 + n < N) v = *(const float4*)&X[(size_t)(gn0 + n) * 128 + kc + k4 * 4];
            xsT[k4 * 4 + 0][n] = v.x;
            xsT[k4 * 4 + 1][n] = v.y;
            xsT[k4 * 4 + 2][n] = v.z;
            xsT[k4 * 4 + 3][n] = v.w;
        }
#pragma unroll
        for (int it = 0; it < WLD; it++) {
            int idx = tid + 256 * it;
            int d = idx / KPF, k4 = idx % KPF;
            float4 v = *(const float4*)&W1[(size_t)d * 128 + kc + k4 * 4];
            wt1[k4 * 4 + 0][d] = v.x;
            wt1[k4 * 4 + 1][d] = v.y;
            wt1[k4 * 4 + 2][d] = v.z;
            wt1[k4 * 4 + 3][d] = v.w;
        }
#pragma unroll
        for (int it = 0; it < WLD; it++) {
            int idx = tid + 256 * it;
            int d = idx / KPF, k4 = idx % KPF;
            float4 v = *(const float4*)&W2[(size_t)d * 128 + kc + k4 * 4];
            wt2[k4 * 4 + 0][d] = v.x;
            wt2[k4 * 4 + 1][d] = v.y;
            wt2[k4 * 4 + 2][d] = v.z;
            wt2[k4 * 4 + 3][d] = v.w;
        }
        __syncthreads();
#pragma unroll
        for (int kk = 0; kk < KC; kk++) {
            float4 xv = *(const float4*)&xsT[kk][n0];
            float4 wa1 = *(const float4*)&wt1[kk][d0];
            float4 wb1 = *(const float4*)&wt1[kk][d1];
            float4 wa2 = *(const float4*)&wt2[kk][d0];
            float4 wb2 = *(const float4*)&wt2[kk][d1];
            float xa[4] = {xv.x, xv.y, xv.z, xv.w};
            float w1a[8] = {wa1.x, wa1.y, wa1.z, wa1.w, wb1.x, wb1.y, wb1.z, wb1.w};
            float w2a[8] = {wa2.x, wa2.y, wa2.z, wa2.w, wb2.x, wb2.y, wb2.z, wb2.w};
#pragma unroll
            for (int i = 0; i < 4; i++)
#pragma unroll
                for (int j = 0; j < 8; j++) {
                    acc1[i][j] += xa[i] * w1a[j];
                    acc2[i][j] += xa[i] * w2a[j];
                }
        }
    }
#pragma unroll
    for (int i = 0; i < 4; i++) {
        int n = gn0 + n0 + i;
        if (n < N) {
            ushort4 sA, sB;
            sA.x = f2bs(acc1[i][0]); sA.y = f2bs(acc1[i][1]);
            sA.z = f2bs(acc1[i][2]); sA.w = f2bs(acc1[i][3]);
            sB.x = f2bs(acc1[i][4]); sB.y = f2bs(acc1[i][5]);
            sB.z = f2bs(acc1[i][6]); sB.w = f2bs(acc1[i][7]);
            *(ushort4*)&Y1b[(size_t)n * BN + d0] = sA;
            *(ushort4*)&Y1b[(size_t)n * BN + d1] = sB;
            *(float4*)&Y2[(size_t)n * BN + d0] =
                make_float4(acc2[i][0], acc2[i][1], acc2[i][2], acc2[i][3]);
            *(float4*)&Y2[(size_t)n * BN + d1] =
                make_float4(acc2[i][4], acc2[i][5], acc2[i][6], acc2[i][7]);
        }
    }
}

// ---------------- fused: layer-1 dual GEMM + hist/rank ----------------
// Blocks [0, GB): dual GEMM over node tiles. Blocks [GB, gridDim): grid-stride
// hist_rank (atomic-latency-bound, VALU-idle) — overlaps with the VALU-bound
// GEMM on the same CUs. Independent work; CSR ordering within a segment is
// arbitrary anyway (sum is commutative; arrival order was never deterministic).
template <int BM, int BN, int KC>
__global__ __launch_bounds__(256) void k_gemm1_hist(const float* __restrict__ X,
                                                    const float* __restrict__ W1,
                                                    const float* __restrict__ W2,
                                                    unsigned short* __restrict__ Y1b,
                                                    float* __restrict__ Y2, int N,
                                                    int GB,
                                                    const int* __restrict__ dst,
                                                    int* __restrict__ cnt,
                                                    int* __restrict__ rank) {
    __shared__ float xsT[KC][BM + 4];
    __shared__ float wt1[KC][BN + 4];
    __shared__ float wt2[KC][BN + 4];
    if ((int)blockIdx.x < GB) {
        gemm_dual_body<BM, BN, KC>(blockIdx.x, X, W1, W2, Y1b, Y2, N, xsT, wt1, wt2);
    } else {
        int base = ((int)blockIdx.x - GB) * 256 + (int)threadIdx.x;
        int stride = ((int)gridDim.x - GB) * 256;
        for (int i = base; i < NE; i += stride)
            rank[i] = atomicAdd(&cnt[dst[i]], 1);
    }
}

// plain dual GEMM (layer 2)
template <int BM, int BN, int KC>
__global__ __launch_bounds__(256) void k_gemm_dual(const float* __restrict__ X,
                                                   const float* __restrict__ W1,
                                                   const float* __restrict__ W2,
                                                   unsigned short* __restrict__ Y1b,
                                                   float* __restrict__ Y2, int N) {
    __shared__ float xsT[KC][BM + 4];
    __shared__ float wt1[KC][BN + 4];
    __shared__ float wt2[KC][BN + 4];
    gemm_dual_body<BM, BN, KC>(blockIdx.x, X, W1, W2, Y1b, Y2, N, xsT, wt1, wt2);
}

// ---------------- aggregation ----------------
// layer 1: one wave per dst; bf16 rows (256B), lane covers dims 2l,2l+1; unroll 4.
// hio: xr on entry, h on exit (row-exclusive in-place).
__global__ __launch_bounds__(256) void k_agg1(const unsigned int* __restrict__ xl32,
                                              float* hio,
                                              const int* __restrict__ offs,
                                              const int2* __restrict__ csr,
                                              const float* __restrict__ bias) {
    int wid = (blockIdx.x * 256 + threadIdx.x) >> 6;
    int lane = threadIdx.x & 63;
    if (wid >= NN) return;
    int s0 = offs[wid], s1 = offs[wid + 1];
    float a0 = 0.f, a1 = 0.f, b0 = 0.f, b1 = 0.f;
    float c0 = 0.f, c1 = 0.f, d0 = 0.f, d1 = 0.f;
    int e = s0;
    for (; e + 4 <= s1; e += 4) {
        int2 cA = csr[e], cB = csr[e + 1], cC = csr[e + 2], cD = csr[e + 3];
        unsigned int rA = xl32[(size_t)cA.x * 64 + lane];
        unsigned int rB = xl32[(size_t)cB.x * 64 + lane];
        unsigned int rC = xl32[(size_t)cC.x * 64 + lane];
        unsigned int rD = xl32[(size_t)cD.x * 64 + lane];
        float wA = __int_as_float(cA.y), wB = __int_as_float(cB.y);
        float wC = __int_as_float(cC.y), wD = __int_as_float(cD.y);
        a0 += wA * blo(rA); a1 += wA * bhi(rA);
        b0 += wB * blo(rB); b1 += wB * bhi(rB);
        c0 += wC * blo(rC); c1 += wC * bhi(rC);
        d0 += wD * blo(rD); d1 += wD * bhi(rD);
    }
    for (; e < s1; ++e) {
        int2 cA = csr[e];
        unsigned int rA = xl32[(size_t)cA.x * 64 + lane];
        float wA = __int_as_float(cA.y);
        a0 += wA * blo(rA); a1 += wA * bhi(rA);
    }
    a0 += b0 + c0 + d0; a1 += b1 + c1 + d1;
    float inv = 1.0f / fmaxf((float)(s1 - s0), 1.0f);
    float2 bz = *(const float2*)&bias[2 * lane];
    float2 r = *(const float2*)&hio[(size_t)wid * 128 + 2 * lane];
    float o0 = fmaxf(a0 * inv + bz.x + r.x, 0.0f);
    float o1 = fmaxf(a1 * inv + bz.y + r.y, 0.0f);
    *(float2*)&hio[(size_t)wid * 128 + 2 * lane] = make_float2(o0, o1);
}

// layer 2: bf16 rows (128B = half wave). Two 32-lane halves process alternate
// edges; combine via shfl_xor(32). oio: hr on entry, logits on exit.
__global__ __launch_bounds__(256) void k_agg2(const unsigned int* __restrict__ hl32,
                                              float* oio,
                                              const int* __restrict__ offs,
                                              const int2* __restrict__ csr,
                                              const float* __restrict__ bias) {
    int wid = (blockIdx.x * 256 + threadIdx.x) >> 6;
    int lane = threadIdx.x & 63;
    if (wid >= NN) return;
    int s0 = offs[wid], s1 = offs[wid + 1];
    int half = lane >> 5, sl = lane & 31;
    float a0 = 0.f, a1 = 0.f, b0 = 0.f, b1 = 0.f;
    int e = s0 + half;
    for (; e + 2 < s1; e += 4) {
        int2 cA = csr[e], cB = csr[e + 2];
        unsigned int rA = hl32[(size_t)cA.x * 32 + sl];
        unsigned int rB = hl32[(size_t)cB.x * 32 + sl];
        float wA = __int_as_float(cA.y), wB = __int_as_float(cB.y);
        a0 += wA * blo(rA); a1 += wA * bhi(rA);
        b0 += wB * blo(rB); b1 += wB * bhi(rB);
    }
    if (e < s1) {
        int2 cA = csr[e];
        unsigned int rA = hl32[(size_t)cA.x * 32 + sl];
        float wA = __int_as_float(cA.y);
        a0 += wA * blo(rA); a1 += wA * bhi(rA);
    }
    a0 += b0; a1 += b1;
    a0 += __shfl_xor(a0, 32);
    a1 += __shfl_xor(a1, 32);
    if (half == 0) {
        float inv = 1.0f / fmaxf((float)(s1 - s0), 1.0f);
        float2 bz = *(const float2*)&bias[2 * sl];
        float2 r = *(const float2*)&oio[(size_t)wid * 64 + 2 * sl];
        *(float2*)&oio[(size_t)wid * 64 + 2 * sl] =
            make_float2(a0 * inv + bz.x + r.x, a1 * inv + bz.y + r.y);
    }
}

// ---------------- launch ----------------

extern "C" void kernel_launch(void* const* d_in, const int* in_sizes, int n_in,
                              void* d_out, int out_size, void* d_ws, size_t ws_size,
                              hipStream_t stream) {
    const float* x   = (const float*)d_in[0];
    const int*   ei  = (const int*)d_in[1];   // [2][NE] int32
    const float* ew  = (const float*)d_in[2];
    const float* Wl1 = (const float*)d_in[3];
    const float* bl1 = (const float*)d_in[4];
    const float* Wr1 = (const float*)d_in[5];
    const float* Wl2 = (const float*)d_in[6];
    const float* bl2 = (const float*)d_in[7];
    const float* Wr2 = (const float*)d_in[8];

    float* h      = (float*)d_out;                  // [NN][128]
    float* logits = h + (size_t)NN * 128;           // [NN][64]

    char* w = (char*)d_ws;
    size_t p = 0;
    auto alloc = [&](size_t bytes) {
        size_t o = p;
        p += (bytes + 255) & ~(size_t)255;
        return o;
    };
    int*   cnt    = (int*)(w + alloc((size_t)NN * 4));
    int*   incl   = (int*)(w + alloc((size_t)NN * 4));
    int*   bsum   = (int*)(w + alloc(4096));
    int*   offs   = (int*)(w + alloc((size_t)(NN + 1) * 4));
    int*   rank   = (int*)(w + alloc((size_t)NE * 4));
    int2*  csr    = (int2*)(w + alloc((size_t)NE * 8));
    unsigned short* xlb = (unsigned short*)(w + alloc((size_t)NN * 128 * 2));
    unsigned short* hlb = xlb;  // layer-2 reuse (dead after k_agg1)
    // total ws use: ~65 MB

    const int* e_src = ei;
    const int* e_dst = ei + NE;

    int nsb = (NN + 1023) / 1024;  // 98 scan blocks

    hipMemsetAsync(cnt, 0, (size_t)NN * 4, stream);

    // fused: layer-1 dual GEMM (blocks [0,GB)) + hist_rank (blocks [GB, GB+2048))
    const int GB = (NN + 63) / 64;  // 1563 gemm blocks
    k_gemm1_hist<64, 128, 32><<<GB + 2048, 256, 0, stream>>>(
        x, Wl1, Wr1, xlb, h, NN, GB, e_dst, cnt, rank);

    k_scan_block<<<nsb, 1024, 0, stream>>>(cnt, incl, bsum, NN);
    k_scan_bsum<<<1, 128, 0, stream>>>(bsum, nsb);
    k_offs<<<(NN + 255) / 256, 256, 0, stream>>>(incl, bsum, offs, NN);
    k_place<<<NE / 256, 256, 0, stream>>>(e_src, e_dst, ew, offs, rank, csr);

    // layer 1 aggregate (in place over h: xr -> h)
    k_agg1<<<(NN + 3) / 4, 256, 0, stream>>>((const unsigned int*)xlb, h, offs, csr, bl1);

    // layer 2: hl (bf16) -> ws, hr (f32) -> logits, in-place aggregate
    k_gemm_dual<128, 64, 32><<<(NN + 127) / 128, 256, 0, stream>>>(h, Wl2, Wr2, hlb, logits, NN);
    k_agg2<<<(NN + 3) / 4, 256, 0, stream>>>((const unsigned int*)hlb, logits, offs, csr, bl2);
}

// Round 7
// 590.474 us; speedup vs baseline: 1.8436x; 1.2036x over previous
//
#include <hip/hip_runtime.h>
#include <hip/hip_bf16.h>

#define NN 100000
#define NE 3200000
#define NB 196          // buckets of 512 nodes (196*512 = 100352 >= NN)
#define BKT_CAP 24576   // slots per bucket; expected 16327 +/- 128 (64 sigma margin)
// D_IN = D_HID = 128, D_OUT = 64

// bf16 (stored as uint packed pair) -> f32 expansion: low/high halves
__device__ inline float blo(unsigned int u) { return __uint_as_float(u << 16); }
__device__ inline float bhi(unsigned int u) { return __uint_as_float(u & 0xffff0000u); }

__device__ inline unsigned short f2bs(float f) {
    __hip_bfloat16 b = __float2bfloat16(f);
    return __builtin_bit_cast(unsigned short, b);
}

// ---------------- CSR build: two-level bucket sort ----------------
// Pass 1: scatter edges into per-bucket segments (bucket = dst>>9).
// Global atomics: one per (block,bucket) reservation = ~50K total
// (vs 3.2M per-edge atomics in the old hist; that was a 140us
// coherence-point-throughput floor at ~23G atomics/s).
__global__ __launch_bounds__(1024) void k_bucket(const int* __restrict__ src,
                                                 const int* __restrict__ dst,
                                                 const float* __restrict__ ew,
                                                 int* __restrict__ bkt_cnt,
                                                 int2* __restrict__ bseg) {
    __shared__ int lcnt[NB];
    __shared__ int lbase[NB];
    const int t = threadIdx.x;
    const int e0 = (int)blockIdx.x * 12500;  // NE = 256 * 12500
    for (int j = t; j < NB; j += 1024) lcnt[j] = 0;
    __syncthreads();
    int br[13];  // packed (rank<<8 | bucket) per iteration — static indices only
#pragma unroll
    for (int it = 0; it < 13; ++it) {
        int i = e0 + it * 1024 + t;
        br[it] = -1;
        if (it * 1024 + t < 12500) {
            int b = dst[i] >> 9;
            int r = atomicAdd(&lcnt[b], 1);   // LDS atomic: local rank
            br[it] = (r << 8) | b;            // r < 12500 (14b), b < 196 (8b)
        }
    }
    __syncthreads();
    for (int j = t; j < NB; j += 1024)
        lbase[j] = atomicAdd(&bkt_cnt[j], lcnt[j]);  // global reservation
    __syncthreads();
#pragma unroll
    for (int it = 0; it < 13; ++it) {
        int i = e0 + it * 1024 + t;
        if (it * 1024 + t < 12500) {
            int b = br[it] & 255;
            int r = br[it] >> 8;
            int d = dst[i];  // L2-hot reload
            bseg[(size_t)b * BKT_CAP + lbase[b] + r] =
                make_int2(src[i] | ((d & 511) << 20), __float_as_int(ew[i]));
        }
    }
}

// Pass 2: one block per bucket. LDS 512-bin histogram + scan gives per-node
// offsets (writes global offs directly — replaces the old 3-kernel scan),
// then LDS-atomic cursors place edges into the final CSR.
__global__ __launch_bounds__(1024) void k_bucket_csr(const int* __restrict__ bkt_cnt,
                                                     const int2* __restrict__ bseg,
                                                     int* __restrict__ offs,
                                                     int2* __restrict__ csr) {
    __shared__ int sbase[256];
    __shared__ int hist[512];
    __shared__ int cur[512];
    const int t = threadIdx.x;
    const int b = blockIdx.x;

    // exclusive prefix over the 196 bucket counts (every block computes it)
    if (t < 256) sbase[t] = (t < NB) ? bkt_cnt[t] : 0;
    __syncthreads();
    for (int off = 1; off < 256; off <<= 1) {
        int v = 0;
        if (t < 256 && t >= off) v = sbase[t - off];
        __syncthreads();
        if (t < 256) sbase[t] += v;
        __syncthreads();
    }
    const int nE = bkt_cnt[b];
    const int out_base = (b == 0) ? 0 : sbase[b - 1];
    const size_t in_base = (size_t)b * BKT_CAP;

    // local histogram of dst&511
    if (t < 512) hist[t] = 0;
    __syncthreads();
    for (int e = t; e < nE; e += 1024)
        atomicAdd(&hist[(bseg[in_base + e].x >> 20) & 511], 1);
    __syncthreads();
    // inclusive scan of 512 counts
    for (int off = 1; off < 512; off <<= 1) {
        int v = 0;
        if (t < 512 && t >= off) v = hist[t - off];
        __syncthreads();
        if (t < 512) hist[t] += v;
        __syncthreads();
    }
    if (t < 512) {
        int excl = (t == 0) ? 0 : hist[t - 1];
        cur[t] = excl;
        int node = b * 512 + t;
        if (node < NN) offs[node] = out_base + excl;
    }
    if (b == NB - 1 && t == 0) offs[NN] = NE;
    __syncthreads();
    // place (order within a node's segment is arbitrary; sum is commutative)
    for (int e = t; e < nE; e += 1024) {
        int2 v = bseg[in_base + e];
        int r = atomicAdd(&cur[(v.x >> 20) & 511], 1);
        csr[out_base + r] = make_int2(v.x & 0xFFFFF, v.y);
    }
}

// ---------------- fused dual f32 GEMM ----------------
// Y1 (bf16) = X @ W1^T ; Y2 (f32) = X @ W2^T. 256 thr; 4 nodes x 8 dims each.

template <int BM, int BN, int KC>
__global__ __launch_bounds__(256) void k_gemm_dual(const float* __restrict__ X,
                                                   const float* __restrict__ W1,
                                                   const float* __restrict__ W2,
                                                   unsigned short* __restrict__ Y1b,
                                                   float* __restrict__ Y2, int N) {
    constexpr int TD = BN / 8;
    constexpr int TN = 256 / TD;
    static_assert(BM / TN == 4, "4 nodes per thread");
    constexpr int KPF = KC / 4;
    constexpr int XLD = BM * KC / (4 * 256);
    constexpr int WLD = BN * KC / (4 * 256);
    static_assert(XLD * 4 * 256 == BM * KC && WLD * 4 * 256 == BN * KC);

    __shared__ float xsT[KC][BM + 4];
    __shared__ float wt1[KC][BN + 4];
    __shared__ float wt2[KC][BN + 4];

    const int tid = threadIdx.x;
    const int td = tid % TD, tn = tid / TD;
    const int n0 = tn * 4;
    const int d0 = td * 4;
    const int d1 = BN / 2 + td * 4;
    const int gn0 = blockIdx.x * BM;

    float acc1[4][8], acc2[4][8];
#pragma unroll
    for (int i = 0; i < 4; i++)
#pragma unroll
        for (int j = 0; j < 8; j++) { acc1[i][j] = 0.0f; acc2[i][j] = 0.0f; }

    for (int kc = 0; kc < 128; kc += KC) {
        __syncthreads();
#pragma unroll
        for (int it = 0; it < XLD; it++) {
            int idx = tid + 256 * it;
            int n = idx / KPF, k4 = idx % KPF;
            float4 v = make_float4(0.f, 0.f, 0.f, 0.f);
            if (gn0 + n < N) v = *(const float4*)&X[(size_t)(gn0 + n) * 128 + kc + k4 * 4];
            xsT[k4 * 4 + 0][n] = v.x;
            xsT[k4 * 4 + 1][n] = v.y;
            xsT[k4 * 4 + 2][n] = v.z;
            xsT[k4 * 4 + 3][n] = v.w;
        }
#pragma unroll
        for (int it = 0; it < WLD; it++) {
            int idx = tid + 256 * it;
            int d = idx / KPF, k4 = idx % KPF;
            float4 v = *(const float4*)&W1[(size_t)d * 128 + kc + k4 * 4];
            wt1[k4 * 4 + 0][d] = v.x;
            wt1[k4 * 4 + 1][d] = v.y;
            wt1[k4 * 4 + 2][d] = v.z;
            wt1[k4 * 4 + 3][d] = v.w;
        }
#pragma unroll
        for (int it = 0; it < WLD; it++) {
            int idx = tid + 256 * it;
            int d = idx / KPF, k4 = idx % KPF;
            float4 v = *(const float4*)&W2[(size_t)d * 128 + kc + k4 * 4];
            wt2[k4 * 4 + 0][d] = v.x;
            wt2[k4 * 4 + 1][d] = v.y;
            wt2[k4 * 4 + 2][d] = v.z;
            wt2[k4 * 4 + 3][d] = v.w;
        }
        __syncthreads();
#pragma unroll
        for (int kk = 0; kk < KC; kk++) {
            float4 xv = *(const float4*)&xsT[kk][n0];
            float4 wa1 = *(const float4*)&wt1[kk][d0];
            float4 wb1 = *(const float4*)&wt1[kk][d1];
            float4 wa2 = *(const float4*)&wt2[kk][d0];
            float4 wb2 = *(const float4*)&wt2[kk][d1];
            float xa[4] = {xv.x, xv.y, xv.z, xv.w};
            float w1a[8] = {wa1.x, wa1.y, wa1.z, wa1.w, wb1.x, wb1.y, wb1.z, wb1.w};
            float w2a[8] = {wa2.x, wa2.y, wa2.z, wa2.w, wb2.x, wb2.y, wb2.z, wb2.w};
#pragma unroll
            for (int i = 0; i < 4; i++)
#pragma unroll
                for (int j = 0; j < 8; j++) {
                    acc1[i][j] += xa[i] * w1a[j];
                    acc2[i][j] += xa[i] * w2a[j];
                }
        }
    }
#pragma unroll
    for (int i = 0; i < 4; i++) {
        int n = gn0 + n0 + i;
        if (n < N) {
            ushort4 sA, sB;
            sA.x = f2bs(acc1[i][0]); sA.y = f2bs(acc1[i][1]);
            sA.z = f2bs(acc1[i][2]); sA.w = f2bs(acc1[i][3]);
            sB.x = f2bs(acc1[i][4]); sB.y = f2bs(acc1[i][5]);
            sB.z = f2bs(acc1[i][6]); sB.w = f2bs(acc1[i][7]);
            *(ushort4*)&Y1b[(size_t)n * BN + d0] = sA;
            *(ushort4*)&Y1b[(size_t)n * BN + d1] = sB;
            *(float4*)&Y2[(size_t)n * BN + d0] =
                make_float4(acc2[i][0], acc2[i][1], acc2[i][2], acc2[i][3]);
            *(float4*)&Y2[(size_t)n * BN + d1] =
                make_float4(acc2[i][4], acc2[i][5], acc2[i][6], acc2[i][7]);
        }
    }
}

// ---------------- aggregation ----------------
// layer 1: one wave per dst; bf16 rows (256B), lane covers dims 2l,2l+1; unroll 4.
// hio: xr on entry, h on exit (row-exclusive in-place).
__global__ __launch_bounds__(256) void k_agg1(const unsigned int* __restrict__ xl32,
                                              float* hio,
                                              const int* __restrict__ offs,
                                              const int2* __restrict__ csr,
                                              const float* __restrict__ bias) {
    int wid = (blockIdx.x * 256 + threadIdx.x) >> 6;
    int lane = threadIdx.x & 63;
    if (wid >= NN) return;
    int s0 = offs[wid], s1 = offs[wid + 1];
    float a0 = 0.f, a1 = 0.f, b0 = 0.f, b1 = 0.f;
    float c0 = 0.f, c1 = 0.f, d0 = 0.f, d1 = 0.f;
    int e = s0;
    for (; e + 4 <= s1; e += 4) {
        int2 cA = csr[e], cB = csr[e + 1], cC = csr[e + 2], cD = csr[e + 3];
        unsigned int rA = xl32[(size_t)cA.x * 64 + lane];
        unsigned int rB = xl32[(size_t)cB.x * 64 + lane];
        unsigned int rC = xl32[(size_t)cC.x * 64 + lane];
        unsigned int rD = xl32[(size_t)cD.x * 64 + lane];
        float wA = __int_as_float(cA.y), wB = __int_as_float(cB.y);
        float wC = __int_as_float(cC.y), wD = __int_as_float(cD.y);
        a0 += wA * blo(rA); a1 += wA * bhi(rA);
        b0 += wB * blo(rB); b1 += wB * bhi(rB);
        c0 += wC * blo(rC); c1 += wC * bhi(rC);
        d0 += wD * blo(rD); d1 += wD * bhi(rD);
    }
    for (; e < s1; ++e) {
        int2 cA = csr[e];
        unsigned int rA = xl32[(size_t)cA.x * 64 + lane];
        float wA = __int_as_float(cA.y);
        a0 += wA * blo(rA); a1 += wA * bhi(rA);
    }
    a0 += b0 + c0 + d0; a1 += b1 + c1 + d1;
    float inv = 1.0f / fmaxf((float)(s1 - s0), 1.0f);
    float2 bz = *(const float2*)&bias[2 * lane];
    float2 r = *(const float2*)&hio[(size_t)wid * 128 + 2 * lane];
    float o0 = fmaxf(a0 * inv + bz.x + r.x, 0.0f);
    float o1 = fmaxf(a1 * inv + bz.y + r.y, 0.0f);
    *(float2*)&hio[(size_t)wid * 128 + 2 * lane] = make_float2(o0, o1);
}

// layer 2: bf16 rows (128B = half wave). Two 32-lane halves process alternate
// edges; combine via shfl_xor(32). oio: hr on entry, logits on exit.
__global__ __launch_bounds__(256) void k_agg2(const unsigned int* __restrict__ hl32,
                                              float* oio,
                                              const int* __restrict__ offs,
                                              const int2* __restrict__ csr,
                                              const float* __restrict__ bias) {
    int wid = (blockIdx.x * 256 + threadIdx.x) >> 6;
    int lane = threadIdx.x & 63;
    if (wid >= NN) return;
    int s0 = offs[wid], s1 = offs[wid + 1];
    int half = lane >> 5, sl = lane & 31;
    float a0 = 0.f, a1 = 0.f, b0 = 0.f, b1 = 0.f;
    int e = s0 + half;
    for (; e + 2 < s1; e += 4) {
        int2 cA = csr[e], cB = csr[e + 2];
        unsigned int rA = hl32[(size_t)cA.x * 32 + sl];
        unsigned int rB = hl32[(size_t)cB.x * 32 + sl];
        float wA = __int_as_float(cA.y), wB = __int_as_float(cB.y);
        a0 += wA * blo(rA); a1 += wA * bhi(rA);
        b0 += wB * blo(rB); b1 += wB * bhi(rB);
    }
    if (e < s1) {
        int2 cA = csr[e];
        unsigned int rA = hl32[(size_t)cA.x * 32 + sl];
        float wA = __int_as_float(cA.y);
        a0 += wA * blo(rA); a1 += wA * bhi(rA);
    }
    a0 += b0; a1 += b1;
    a0 += __shfl_xor(a0, 32);
    a1 += __shfl_xor(a1, 32);
    if (half == 0) {
        float inv = 1.0f / fmaxf((float)(s1 - s0), 1.0f);
        float2 bz = *(const float2*)&bias[2 * sl];
        float2 r = *(const float2*)&oio[(size_t)wid * 64 + 2 * sl];
        *(float2*)&oio[(size_t)wid * 64 + 2 * sl] =
            make_float2(a0 * inv + bz.x + r.x, a1 * inv + bz.y + r.y);
    }
}

// ---------------- launch ----------------

extern "C" void kernel_launch(void* const* d_in, const int* in_sizes, int n_in,
                              void* d_out, int out_size, void* d_ws, size_t ws_size,
                              hipStream_t stream) {
    const float* x   = (const float*)d_in[0];
    const int*   ei  = (const int*)d_in[1];   // [2][NE] int32
    const float* ew  = (const float*)d_in[2];
    const float* Wl1 = (const float*)d_in[3];
    const float* bl1 = (const float*)d_in[4];
    const float* Wr1 = (const float*)d_in[5];
    const float* Wl2 = (const float*)d_in[6];
    const float* bl2 = (const float*)d_in[7];
    const float* Wr2 = (const float*)d_in[8];

    float* h      = (float*)d_out;                  // [NN][128]
    float* logits = h + (size_t)NN * 128;           // [NN][64]

    char* w = (char*)d_ws;
    size_t p = 0;
    auto alloc = [&](size_t bytes) {
        size_t o = p;
        p += (bytes + 255) & ~(size_t)255;
        return o;
    };
    int*   bkt_cnt = (int*)(w + alloc((size_t)NB * 4));
    int*   offs    = (int*)(w + alloc((size_t)(NN + 1) * 4));
    int2*  csr     = (int2*)(w + alloc((size_t)NE * 8));
    int2*  bseg    = (int2*)(w + alloc((size_t)NB * BKT_CAP * 8));  // 38.5 MB
    // bseg is dead after k_bucket_csr; xl/hl (25.6 MB) alias it.
    unsigned short* xlb = (unsigned short*)bseg;
    unsigned short* hlb = xlb;
    // total ws use: ~64.6 MB

    const int* e_src = ei;
    const int* e_dst = ei + NE;

    hipMemsetAsync(bkt_cnt, 0, (size_t)NB * 4, stream);
    k_bucket<<<256, 1024, 0, stream>>>(e_src, e_dst, ew, bkt_cnt, bseg);
    k_bucket_csr<<<NB, 1024, 0, stream>>>(bkt_cnt, bseg, offs, csr);

    // layer 1: xl (bf16) -> ws (aliases dead bseg), xr (f32) -> h, aggregate
    k_gemm_dual<64, 128, 32><<<(NN + 63) / 64, 256, 0, stream>>>(x, Wl1, Wr1, xlb, h, NN);
    k_agg1<<<(NN + 3) / 4, 256, 0, stream>>>((const unsigned int*)xlb, h, offs, csr, bl1);

    // layer 2: hl (bf16) -> ws, hr (f32) -> logits, in-place aggregate
    k_gemm_dual<128, 64, 32><<<(NN + 127) / 128, 256, 0, stream>>>(h, Wl2, Wr2, hlb, logits, NN);
    k_agg2<<<(NN + 3) / 4, 256, 0, stream>>>((const unsigned int*)hlb, logits, offs, csr, bl2);
}